// Round 7
// baseline (14878.975 us; speedup 1.0000x reference)
//
#include <hip/hip_runtime.h>
#include <hip/hip_fp16.h>
#include <hip/hip_bf16.h>

#define Bb 8
#define Nn 10000
#define Ee 320000
#define HIST 24
#define PRED 12
#define BN (Bb * Nn)

__device__ __forceinline__ float sigm(float x) { return 1.0f / (1.0f + __expf(-x)); }
__device__ __forceinline__ float tanh_fast(float x) { return 1.0f - 2.0f / (__expf(2.0f * x) + 1.0f); }

__device__ __forceinline__ void load16f(const float* p, float* o) {
  const float4* q = reinterpret_cast<const float4*>(p);
  float4 a = q[0], b = q[1], c = q[2], d = q[3];
  o[0] = a.x; o[1] = a.y; o[2]  = a.z; o[3]  = a.w;
  o[4] = b.x; o[5] = b.y; o[6]  = b.z; o[7]  = b.w;
  o[8] = c.x; o[9] = c.y; o[10] = c.z; o[11] = c.w;
  o[12] = d.x; o[13] = d.y; o[14] = d.z; o[15] = d.w;
}

// full edge MLP (fallback paths): in[35] -> sigm(35x32) -> sigm(32x30)
__device__ __forceinline__ void edge_mlp(const float* __restrict__ in,
                                         const float* __restrict__ W,
                                         float* __restrict__ h2) {
  const float* w1 = W;
  const float* b1 = W + 1120;
  const float* w2 = W + 1152;
  const float* b2 = W + 2112;
  float h1[32];
#pragma unroll
  for (int j = 0; j < 32; j++) h1[j] = b1[j];
#pragma unroll
  for (int k = 0; k < 35; k++) {
    float v = in[k];
#pragma unroll
    for (int j = 0; j < 32; j++) h1[j] = fmaf(v, w1[k * 32 + j], h1[j]);
  }
#pragma unroll
  for (int j = 0; j < 32; j++) h1[j] = sigm(h1[j]);
#pragma unroll
  for (int j = 0; j < 30; j++) h2[j] = b2[j];
#pragma unroll
  for (int k = 0; k < 32; k++) {
    float v = h1[k];
#pragma unroll
    for (int j = 0; j < 30; j++) h2[j] = fmaf(v, w2[k * 30 + j], h2[j]);
  }
#pragma unroll
  for (int j = 0; j < 30; j++) h2[j] = sigm(h2[j]);
}

// contiguous-h variant (mid/small fallback paths)
__device__ __forceinline__ void gru_out(const float* __restrict__ agg,
                                        const float* __restrict__ W,
                                        const float* __restrict__ featp,
                                        float xn_old,
                                        float* __restrict__ xn_new_slot,
                                        float* __restrict__ hp,
                                        float* __restrict__ out_slot) {
  const float* nw  = W + 2142;
  const float* nb  = W + 2532;
  const float* wih = W + 2545;
  const float* whh = W + 8305;
  const float* bih = W + 20593;
  const float* bhh = W + 20785;
  const float* fw  = W + 20977;
  const float* fcb = W + 21041;
  float xin[30];
#pragma unroll
  for (int j = 0; j < 13; j++) {
    float a = nb[j];
#pragma unroll
    for (int k = 0; k < 30; k++) a = fmaf(agg[k], nw[k * 13 + j], a);
    xin[j] = sigm(a);
  }
  xin[13] = xn_old;
  load16f(featp, xin + 14);
  float h[64];
#pragma unroll
  for (int j = 0; j < 64; j++) h[j] = hp[j];
  float xnew = fcb[0];
  for (int j = 0; j < 64; j++) {
    float ir = bih[j], iz = bih[64 + j], inn = bih[128 + j];
    const float* wr = wih + j * 30;
    const float* wz = wih + (64 + j) * 30;
    const float* wn = wih + (128 + j) * 30;
#pragma unroll
    for (int k = 0; k < 30; k++) {
      ir  = fmaf(xin[k], wr[k], ir);
      iz  = fmaf(xin[k], wz[k], iz);
      inn = fmaf(xin[k], wn[k], inn);
    }
    float hr = bhh[j], hz = bhh[64 + j], hn_ = bhh[128 + j];
    const float* vr = whh + j * 64;
    const float* vz = whh + (64 + j) * 64;
    const float* vn = whh + (128 + j) * 64;
#pragma unroll
    for (int k = 0; k < 64; k++) {
      hr  = fmaf(h[k], vr[k], hr);
      hz  = fmaf(h[k], vz[k], hz);
      hn_ = fmaf(h[k], vn[k], hn_);
    }
    float rg = sigm(ir + hr);
    float zg = sigm(iz + hz);
    float ng = tanh_fast(inn + rg * hn_);
    float hnew = (1.f - zg) * ng + zg * h[j];
    hp[j] = hnew;
    xnew = fmaf(hnew, fw[j], xnew);
  }
  *xn_new_slot = xnew;
  *out_slot = xnew;
}

// ---------- preprocessing ----------

__global__ void k_stats(const float* __restrict__ ea, float* __restrict__ stats) {
  __shared__ float s1[256], s2[256];
  int tid = threadIdx.x;
  int i = blockIdx.x * 256 + tid;
  float v = 0.f;
  if (i < Ee) v = ea[i];
  s1[tid] = v;
  s2[tid] = v * v;
  __syncthreads();
  for (int o = 128; o > 0; o >>= 1) {
    if (tid < o) { s1[tid] += s1[tid + o]; s2[tid] += s2[tid + o]; }
    __syncthreads();
  }
  if (tid == 0) { atomicAdd(&stats[0], s1[0]); atomicAdd(&stats[1], s2[0]); }
}

__global__ void k_finalize_stats(float* stats) {
  float sum = stats[0], sumsq = stats[1];
  float mean = sum / (float)Ee;
  float var = (sumsq - sum * mean) / (float)(Ee - 1);
  stats[2] = mean;
  stats[3] = rsqrtf(var);
}

__global__ void k_hist(const int* __restrict__ eidx, int* __restrict__ deg_t, int* __restrict__ deg_s) {
  int e = blockIdx.x * 256 + threadIdx.x;
  if (e >= Ee) return;
  atomicAdd(&deg_s[eidx[e]], 1);
  atomicAdd(&deg_t[eidx[Ee + e]], 1);
}

__global__ void k_scan(const int* __restrict__ deg_t, int* __restrict__ off_t,
                       const int* __restrict__ deg_s, int* __restrict__ off_s) {
  const int* deg = (blockIdx.x == 0) ? deg_t : deg_s;
  int* off = (blockIdx.x == 0) ? off_t : off_s;
  __shared__ int s[1024];
  __shared__ int carry;
  int tid = threadIdx.x;
  if (tid == 0) carry = 0;
  __syncthreads();
  for (int base = 0; base < Nn; base += 1024) {
    int v = (base + tid < Nn) ? deg[base + tid] : 0;
    s[tid] = v;
    int val = v;
    __syncthreads();
    for (int o = 1; o < 1024; o <<= 1) {
      int tv = (tid >= o) ? s[tid - o] : 0;
      __syncthreads();
      val += tv;
      s[tid] = val;
      __syncthreads();
    }
    if (base + tid < Nn) off[base + tid] = carry + (val - v);
    __syncthreads();
    if (tid == 1023) carry += val;
    __syncthreads();
  }
  if (tid == 0) off[Nn] = carry;
}

__global__ void k_fill(const int* __restrict__ eidx,
                       const int* __restrict__ off_t, const int* __restrict__ off_s,
                       int* __restrict__ cur_t, int* __restrict__ cur_s,
                       int* __restrict__ list_t, int* __restrict__ list_s) {
  int e = blockIdx.x * 256 + threadIdx.x;
  if (e >= Ee) return;
  int s = eidx[e], t = eidx[Ee + e];
  int ps = off_s[s] + atomicAdd(&cur_s[s], 1);
  list_s[ps] = e;
  int pt = off_t[t] + atomicAdd(&cur_t[t], 1);
  list_t[pt] = e;
}

__global__ void k_convert(const float* w1, const float* b1, const float* w2, const float* b2,
                          const float* nw, const float* nb, const float* wih, const float* whh,
                          const float* bih, const float* bhh, const float* fw, const float* fb,
                          float* __restrict__ dst) {
  int i = blockIdx.x * 256 + threadIdx.x;
  const int c1 = 1120, c2 = 1152, c3 = 2112, c4 = 2142, c5 = 2532, c6 = 2545,
            c7 = 8305, c8 = 20593, c9 = 20785, c10 = 20977, c11 = 21041, c12 = 21042;
  if (i >= c12) return;
  const float* p;
  int base;
  if (i < c1)       { p = w1;  base = 0;  }
  else if (i < c2)  { p = b1;  base = c1; }
  else if (i < c3)  { p = w2;  base = c2; }
  else if (i < c4)  { p = b2;  base = c3; }
  else if (i < c5)  { p = nw;  base = c4; }
  else if (i < c6)  { p = nb;  base = c5; }
  else if (i < c7)  { p = wih; base = c6; }
  else if (i < c8)  { p = whh; base = c7; }
  else if (i < c9)  { p = bih; base = c8; }
  else if (i < c10) { p = bhh; base = c9; }
  else if (i < c11) { p = fw;  base = c10; }
  else              { p = fb;  base = c11; }
  dst[i] = p[i - base];
}

__global__ void k_xn0(const float* __restrict__ t2m, float* __restrict__ xn) {
  int i = blockIdx.x * 256 + threadIdx.x;
  if (i >= BN) return;
  int b = i / Nn, n = i % Nn;
  xn[i] = t2m[((size_t)b * HIST + (HIST - 1)) * Nn + n];
}

// ---------- big2 path: hoisted layer-1 ----------

__global__ __launch_bounds__(256) void k_pre_edge(
    const float* __restrict__ feat, const float* __restrict__ xn,
    const float* __restrict__ W, float* __restrict__ as_, float* __restrict__ at_, int t) {
  int idx = blockIdx.x * 256 + threadIdx.x;
  if (idx >= BN) return;
  int b = idx / Nn, n = idx % Nn;
  const float* w1 = W;
  const float* b1 = W + 1120;
  float f[16];
  const float* fbp = feat + ((size_t)(b * (HIST + PRED) + HIST + t)) * Nn * 16 + (size_t)n * 16;
  load16f(fbp, f);
  float x = xn[idx];
  float as[32], at[32];
#pragma unroll
  for (int j = 0; j < 32; j++) {
    as[j] = fmaf(x, w1[j], b1[j]);          // row 0
    at[j] = x * w1[17 * 32 + j];            // row 17
  }
#pragma unroll
  for (int k = 0; k < 16; k++) {
    float v = f[k];
#pragma unroll
    for (int j = 0; j < 32; j++) {
      as[j] = fmaf(v, w1[(1 + k) * 32 + j], as[j]);
      at[j] = fmaf(v, w1[(18 + k) * 32 + j], at[j]);
    }
  }
  float4* ap = (float4*)(as_ + (size_t)idx * 32);
  float4* bp = (float4*)(at_ + (size_t)idx * 32);
#pragma unroll
  for (int q = 0; q < 8; q++) {
    ap[q] = make_float4(as[4 * q], as[4 * q + 1], as[4 * q + 2], as[4 * q + 3]);
    bp[q] = make_float4(at[4 * q], at[4 * q + 1], at[4 * q + 2], at[4 * q + 3]);
  }
}

// fused edge-recompute + gather: replaces k_edge2 + k_gather (+ h2buf traffic).
// 256 threads = 128 nodes x 2 roles. role 0: '+' over list_t (own row = at_,
// neighbor = as_[src]); role 1: '-' over list_s (own row = as_, neighbor =
// at_[tgt]). Per visit recompute edge-MLP layer 2 from the hoisted layer-1
// partials (per-b as_/at_ slices are 2x1.28MB -> L2-resident). All inner
// loops statically unrolled (rule #20). launch_bounds(256,2): 256-VGPR
// budget so the ~124-float live set stays in registers (no scratch).
__global__ __launch_bounds__(256, 2) void k_egather(
    const int* __restrict__ eidx, const float* __restrict__ ea,
    const int* __restrict__ off_t, const int* __restrict__ list_t,
    const int* __restrict__ off_s, const int* __restrict__ list_s,
    const float* __restrict__ as_, const float* __restrict__ at_,
    const float* __restrict__ W, const float* __restrict__ stats,
    float* __restrict__ agg_out) {
  __shared__ float sagg[128 * 30];
  const int tid = threadIdx.x;
  const int m = tid & 127;
  const int role = tid >> 7;                  // wave-uniform (waves 0,1 vs 2,3)
  const int blk0 = blockIdx.x * 128;
  const int node = blk0 + m;                  // BN = 625*128 exactly
  const int b = node / Nn, n = node % Nn;
  const float mean = stats[2], istd = stats[3];
  const float* w1e = W + 1088;   // w1 row 34 (edge-attr row)
  const float* w2  = W + 1152;
  const float* b2  = W + 2112;

  // own layer-1 partial row
  float own[32];
  {
    const float4* q = (const float4*)((role ? as_ : at_) + (size_t)(b * Nn + n) * 32);
#pragma unroll
    for (int i = 0; i < 8; i++) {
      float4 v = q[i];
      own[4 * i] = v.x; own[4 * i + 1] = v.y; own[4 * i + 2] = v.z; own[4 * i + 3] = v.w;
    }
  }
  const int* off = role ? off_s : off_t;
  const int* lst = role ? list_s : list_t;
  const int* nbx = role ? (eidx + Ee) : eidx;
  const float* nbase = role ? at_ : as_;

  float agg[30];
#pragma unroll
  for (int i = 0; i < 30; i++) agg[i] = 0.f;

  const int p1 = off[n + 1];
  for (int p = off[n]; p < p1; p++) {
    int e = lst[p];
    int nb = nbx[e];
    float ean = (ea[e] - mean) * istd;
    const float4* nq = (const float4*)(nbase + (size_t)(b * Nn + nb) * 32);
    float h1[32];
#pragma unroll
    for (int i = 0; i < 8; i++) {
      float4 v = nq[i];
      h1[4 * i]     = sigm(fmaf(ean, w1e[4 * i],     own[4 * i]     + v.x));
      h1[4 * i + 1] = sigm(fmaf(ean, w1e[4 * i + 1], own[4 * i + 1] + v.y));
      h1[4 * i + 2] = sigm(fmaf(ean, w1e[4 * i + 2], own[4 * i + 2] + v.z));
      h1[4 * i + 3] = sigm(fmaf(ean, w1e[4 * i + 3], own[4 * i + 3] + v.w));
    }
    float h2[30];
#pragma unroll
    for (int j = 0; j < 30; j++) h2[j] = b2[j];
#pragma unroll
    for (int k = 0; k < 32; k++) {
      float v = h1[k];
#pragma unroll
      for (int j = 0; j < 30; j++) h2[j] = fmaf(v, w2[k * 30 + j], h2[j]);
    }
#pragma unroll
    for (int j = 0; j < 30; j++) agg[j] += sigm(h2[j]);
  }

  if (role == 1) {
#pragma unroll
    for (int j = 0; j < 30; j++) sagg[m * 30 + j] = agg[j];
  }
  __syncthreads();
  if (role == 0) {
#pragma unroll
    for (int j = 0; j < 30; j++) sagg[m * 30 + j] = agg[j] - sagg[m * 30 + j];
  }
  __syncthreads();
  // cooperative contiguous write: 128*30 = 3840 floats = 960 float4
  {
    float4* dst = (float4*)(agg_out + (size_t)blk0 * 30);
    const float4* src4 = (const float4*)sagg;
#pragma unroll
    for (int r = 0; r < 4; r++) {
      int i = r * 256 + tid;
      if (i < 960) dst[i] = src4[i];
    }
  }
}

// old hoisted edge kernel + channel-parallel gather (fallback path, unused in big2)
__global__ __launch_bounds__(256) void k_edge(
    const int* __restrict__ eidx, const float* __restrict__ ea,
    const float* __restrict__ feat, const float* __restrict__ xn,
    const float* __restrict__ W, const float* __restrict__ stats,
    __half* __restrict__ h2out, int t) {
  int e = blockIdx.x * 256 + threadIdx.x;
  int b = blockIdx.y;
  if (e >= Ee) return;
  float mean = stats[2], istd = stats[3];
  int s = eidx[e], tg = eidx[Ee + e];
  float in[35];
  in[0]  = xn[b * Nn + s];
  in[17] = xn[b * Nn + tg];
  in[34] = (ea[e] - mean) * istd;
  const float* fb = feat + ((size_t)(b * (HIST + PRED) + HIST + t)) * Nn * 16;
  load16f(fb + (size_t)s * 16, in + 1);
  load16f(fb + (size_t)tg * 16, in + 18);
  float h2[30];
  edge_mlp(in, W, h2);
  __half2* o = (__half2*)(h2out + ((size_t)b * Ee + e) * 30);
#pragma unroll
  for (int i = 0; i < 15; i++) o[i] = __floats2half2_rn(h2[2 * i], h2[2 * i + 1]);
}

__global__ __launch_bounds__(256) void k_gather(
    const int* __restrict__ off_t, const int* __restrict__ list_t,
    const int* __restrict__ off_s, const int* __restrict__ list_s,
    const __half* __restrict__ h2, float* __restrict__ agg) {
  int tid = threadIdx.x;
  int c = tid & 31;
  int idx = blockIdx.x * 8 + (tid >> 5);
  if (idx >= BN || c >= 30) return;
  int b = idx / Nn, n = idx % Nn;
  const __half* base = h2 + (size_t)b * Ee * 30;
  float a = 0.f;
  int p0 = off_t[n], p1 = off_t[n + 1];
  int p = p0;
  for (; p + 4 <= p1; p += 4) {
    int e0 = list_t[p], e1 = list_t[p + 1], e2 = list_t[p + 2], e3 = list_t[p + 3];
    float v0 = __half2float(base[(size_t)e0 * 30 + c]);
    float v1 = __half2float(base[(size_t)e1 * 30 + c]);
    float v2 = __half2float(base[(size_t)e2 * 30 + c]);
    float v3 = __half2float(base[(size_t)e3 * 30 + c]);
    a += (v0 + v1) + (v2 + v3);
  }
  for (; p < p1; p++) a += __half2float(base[(size_t)list_t[p] * 30 + c]);
  p0 = off_s[n]; p1 = off_s[n + 1];
  p = p0;
  for (; p + 4 <= p1; p += 4) {
    int e0 = list_s[p], e1 = list_s[p + 1], e2 = list_s[p + 2], e3 = list_s[p + 3];
    float v0 = __half2float(base[(size_t)e0 * 30 + c]);
    float v1 = __half2float(base[(size_t)e1 * 30 + c]);
    float v2 = __half2float(base[(size_t)e2 * 30 + c]);
    float v3 = __half2float(base[(size_t)e3 * 30 + c]);
    a -= (v0 + v1) + (v2 + v3);
  }
  for (; p < p1; p++) a -= __half2float(base[(size_t)list_s[p] * 30 + c]);
  agg[(size_t)idx * 30 + c] = a;
}

// ---------- GRU: 4 waves per 64 nodes, j-split across waves, old-h in LDS ----------
// (round-2 winner, verbatim: duplicated per-thread prologue — measured 172us,
// FETCH 84MB; both de-dup restructures regressed to 274us / 308MB.)
#define HS_STRIDE 68

__global__ __launch_bounds__(256, 4) void k_gru4(
    const float* __restrict__ agg_all, const float* __restrict__ W,
    const float* __restrict__ feat, const float* __restrict__ xn_cur,
    float* __restrict__ xn_nxt, float* __restrict__ hbuf,
    float* __restrict__ out, int t) {
  __shared__ float hs[64 * HS_STRIDE];
  __shared__ float sx[4][64];

  const int tid = threadIdx.x;
  const int lane = tid & 63;
  const int wave = (int)__builtin_amdgcn_readfirstlane(tid >> 6);
  const int node = blockIdx.x * 64 + lane;      // BN = 1250*64 exactly
  const int b = node / Nn, n = node % Nn;

  const float* nw  = W + 2142;
  const float* nb  = W + 2532;
  const float* wih = W + 2545;
  const float* whh = W + 8305;
  const float* bih = W + 20593;
  const float* bhh = W + 20785;
  const float* fw  = W + 20977;
  const float* fcb = W + 21041;

  // ---- stage old h: wave w loads k-rows [16w,16w+16) (coalesced), LDS transpose
  float* hp = hbuf + node;
  {
    const int k0 = wave * 16;
#pragma unroll
    for (int kk = 0; kk < 16; kk++) {
      int k = k0 + kk;
      hs[lane * HS_STRIDE + k] = hp[(size_t)k * BN];
    }
  }

  // ---- node MLP -> xin[0..12] (duplicated per wave; cheap, hides LDS stage)
  float xin[30];
  {
    float agg[30];
    const float* ap = agg_all + (size_t)node * 30;
#pragma unroll
    for (int i = 0; i < 30; i++) agg[i] = ap[i];
#pragma unroll
    for (int j = 0; j < 13; j++) {
      float a = nb[j];
#pragma unroll
      for (int k = 0; k < 30; k++) a = fmaf(agg[k], nw[k * 13 + j], a);
      xin[j] = sigm(a);
    }
  }
  xin[13] = xn_cur[node];
  const float* fbp = feat + ((size_t)(b * (HIST + PRED) + HIST + t)) * Nn * 16 + (size_t)n * 16;
  load16f(fbp, xin + 14);

  __syncthreads();   // old h fully staged in LDS

  const int j0 = wave * 16;
  const float* hrow = hs + lane * HS_STRIDE;
  float xpart = 0.f;
  for (int jj = 0; jj < 16; jj++) {
    const int j = j0 + jj;      // wave-uniform -> weight rows stay scalar loads
    float ir = bih[j], iz = bih[64 + j], inn = bih[128 + j];
    const float* wr = wih + j * 30;
    const float* wz = wih + (64 + j) * 30;
    const float* wn = wih + (128 + j) * 30;
#pragma unroll
    for (int k = 0; k < 30; k++) {
      ir  = fmaf(xin[k], wr[k], ir);
      iz  = fmaf(xin[k], wz[k], iz);
      inn = fmaf(xin[k], wn[k], inn);
    }
    float hr = bhh[j], hz = bhh[64 + j], hn_ = bhh[128 + j];
    const float* vr = whh + j * 64;
    const float* vz = whh + (64 + j) * 64;
    const float* vn = whh + (128 + j) * 64;
#pragma unroll
    for (int k4 = 0; k4 < 16; k4++) {
      float4 h4 = *reinterpret_cast<const float4*>(hrow + k4 * 4);
      hr  = fmaf(h4.x, vr[4 * k4],     hr);
      hz  = fmaf(h4.x, vz[4 * k4],     hz);
      hn_ = fmaf(h4.x, vn[4 * k4],     hn_);
      hr  = fmaf(h4.y, vr[4 * k4 + 1], hr);
      hz  = fmaf(h4.y, vz[4 * k4 + 1], hz);
      hn_ = fmaf(h4.y, vn[4 * k4 + 1], hn_);
      hr  = fmaf(h4.z, vr[4 * k4 + 2], hr);
      hz  = fmaf(h4.z, vz[4 * k4 + 2], hz);
      hn_ = fmaf(h4.z, vn[4 * k4 + 2], hn_);
      hr  = fmaf(h4.w, vr[4 * k4 + 3], hr);
      hz  = fmaf(h4.w, vz[4 * k4 + 3], hz);
      hn_ = fmaf(h4.w, vn[4 * k4 + 3], hn_);
    }
    float holdj = hrow[j];      // single ds_read_b32, no register indexing
    float rg = sigm(ir + hr);
    float zg = sigm(iz + hz);
    float ng = tanh_fast(inn + rg * hn_);
    float hnew = (1.f - zg) * ng + zg * holdj;
    hp[(size_t)j * BN] = hnew;  // coalesced 256B store per (wave, j)
    xpart = fmaf(hnew, fw[j], xpart);
  }

  // reduce fc_out partials across the 4 waves
  sx[wave][lane] = xpart;
  __syncthreads();
  if (wave == 0) {
    float xnew = fcb[0] + ((sx[0][lane] + sx[1][lane]) + (sx[2][lane] + sx[3][lane]));
    xn_nxt[node] = xnew;
    out[((size_t)b * PRED + t) * Nn + n] = xnew;
  }
}

// ---------- mid path: fused gather+GRU ----------

__global__ __launch_bounds__(64) void k_node_g(
    const int* __restrict__ off_t, const int* __restrict__ list_t,
    const int* __restrict__ off_s, const int* __restrict__ list_s,
    const __half* __restrict__ h2, const float* __restrict__ W,
    const float* __restrict__ feat, const float* __restrict__ xn_cur,
    float* __restrict__ xn_nxt,
    float* __restrict__ hbuf, float* __restrict__ out, int t) {
  int n = blockIdx.x * 64 + threadIdx.x;
  int b = blockIdx.y;
  if (n >= Nn) return;
  float agg[30];
#pragma unroll
  for (int i = 0; i < 30; i++) agg[i] = 0.f;
  int p0 = off_t[n], p1 = off_t[n + 1];
  for (int p = p0; p < p1; p++) {
    int e = list_t[p];
    const __half2* r = (const __half2*)(h2 + ((size_t)b * Ee + e) * 30);
#pragma unroll
    for (int i = 0; i < 15; i++) {
      __half2 v = r[i];
      agg[2 * i]     += __low2float(v);
      agg[2 * i + 1] += __high2float(v);
    }
  }
  p0 = off_s[n]; p1 = off_s[n + 1];
  for (int p = p0; p < p1; p++) {
    int e = list_s[p];
    const __half2* r = (const __half2*)(h2 + ((size_t)b * Ee + e) * 30);
#pragma unroll
    for (int i = 0; i < 15; i++) {
      __half2 v = r[i];
      agg[2 * i]     -= __low2float(v);
      agg[2 * i + 1] -= __high2float(v);
    }
  }
  const float* fbp = feat + ((size_t)(b * (HIST + PRED) + HIST + t)) * Nn * 16 + (size_t)n * 16;
  gru_out(agg, W, fbp, xn_cur[b * Nn + n], &xn_nxt[b * Nn + n],
          hbuf + ((size_t)b * Nn + n) * 64, &out[((size_t)b * PRED + t) * Nn + n]);
}

// ---------- small path: recompute ----------

__global__ __launch_bounds__(128) void k_node_rc(
    const int* __restrict__ eidx, const float* __restrict__ ea,
    const int* __restrict__ off_t, const int* __restrict__ list_t,
    const int* __restrict__ off_s, const int* __restrict__ list_s,
    const float* __restrict__ W, const float* __restrict__ stats,
    const float* __restrict__ feat, const float* __restrict__ xn_cur,
    float* __restrict__ xn_nxt,
    float* __restrict__ hbuf, float* __restrict__ out, int t) {
  int idx = blockIdx.x * 128 + threadIdx.x;
  if (idx >= BN) return;
  int b = idx / Nn, n = idx % Nn;
  float mean = stats[2], istd = stats[3];
  const float* fslice = feat + ((size_t)(b * (HIST + PRED) + HIST + t)) * Nn * 16;
  float xo = xn_cur[b * Nn + n];
  float fo[16];
  load16f(fslice + (size_t)n * 16, fo);
  float agg[30];
#pragma unroll
  for (int i = 0; i < 30; i++) agg[i] = 0.f;
  float in[35], h2e[30];
  int p0 = off_t[n], p1 = off_t[n + 1];
  for (int p = p0; p < p1; p++) {
    int e = list_t[p];
    int s = eidx[e];
    in[0] = xn_cur[b * Nn + s];
    load16f(fslice + (size_t)s * 16, in + 1);
    in[17] = xo;
#pragma unroll
    for (int i = 0; i < 16; i++) in[18 + i] = fo[i];
    in[34] = (ea[e] - mean) * istd;
    edge_mlp(in, W, h2e);
#pragma unroll
    for (int i = 0; i < 30; i++) agg[i] += h2e[i];
  }
  p0 = off_s[n]; p1 = off_s[n + 1];
  for (int p = p0; p < p1; p++) {
    int e = list_s[p];
    int tg = eidx[Ee + e];
    in[0] = xo;
#pragma unroll
    for (int i = 0; i < 16; i++) in[1 + i] = fo[i];
    in[17] = xn_cur[b * Nn + tg];
    load16f(fslice + (size_t)tg * 16, in + 18);
    in[34] = (ea[e] - mean) * istd;
    edge_mlp(in, W, h2e);
#pragma unroll
    for (int i = 0; i < 30; i++) agg[i] -= h2e[i];
  }
  gru_out(agg, W, fslice + (size_t)n * 16, xo, &xn_nxt[b * Nn + n],
          hbuf + ((size_t)b * Nn + n) * 64, &out[((size_t)b * PRED + t) * Nn + n]);
}

// ---------- launch ----------

extern "C" void kernel_launch(void* const* d_in, const int* in_sizes, int n_in,
                              void* d_out, int out_size, void* d_ws, size_t ws_size,
                              hipStream_t stream) {
  const float* t2m  = (const float*)d_in[0];
  const float* feat = (const float*)d_in[1];
  const int*   eidx = (const int*)d_in[2];
  const float* ea   = (const float*)d_in[3];
  const float* w1   = (const float*)d_in[4];
  const float* b1   = (const float*)d_in[5];
  const float* w2   = (const float*)d_in[6];
  const float* b2   = (const float*)d_in[7];
  const float* nw   = (const float*)d_in[8];
  const float* nb   = (const float*)d_in[9];
  const float* wih  = (const float*)d_in[10];
  const float* whh  = (const float*)d_in[11];
  const float* bih  = (const float*)d_in[12];
  const float* bhh  = (const float*)d_in[13];
  const float* fw   = (const float*)d_in[14];
  const float* fb   = (const float*)d_in[15];
  float* out = (float*)d_out;

  float* ws = (float*)d_ws;
  float* stats = ws;                                   // 4
  int* deg_t = (int*)(ws + 4);                         // N
  int* deg_s = deg_t + Nn;                             // N
  int* cur_t = deg_s + Nn;                             // N
  int* cur_s = cur_t + Nn;                             // N
  float* hbuf = (float*)(cur_s + Nn);                  // B*N*64 (zeroed; transposed layout in big paths)
  int* off_t = (int*)(hbuf + (size_t)BN * 64);         // N+1
  int* off_s = off_t + (Nn + 1);                       // N+1
  int* list_t = off_s + (Nn + 1);                      // E
  int* list_s = list_t + Ee;                           // E
  float* Wf = (float*)(list_s + Ee);                   // 21056
  float* xnA = Wf + 21056;                             // B*N
  float* xnB = xnA + BN;                               // B*N
  float* base_end = xnB + BN;
  size_t base_bytes = (size_t)((char*)base_end - (char*)d_ws);
  base_bytes = (base_bytes + 15) & ~(size_t)15;
  __half* h2buf = (__half*)((char*)d_ws + base_bytes); // B*E*30 halves (fallback tiers only)
  size_t mid_bytes = base_bytes + (size_t)Bb * Ee * 30 * sizeof(__half);
  mid_bytes = (mid_bytes + 15) & ~(size_t)15;
  float* aggbuf = (float*)((char*)d_ws + mid_bytes);   // B*N*30
  size_t big_bytes = mid_bytes + (size_t)BN * 30 * sizeof(float);
  big_bytes = (big_bytes + 15) & ~(size_t)15;
  float* asbuf = (float*)((char*)d_ws + big_bytes);    // B*N*32
  float* atbuf = asbuf + (size_t)BN * 32;              // B*N*32
  size_t need_big2 = big_bytes + 2 * (size_t)BN * 32 * sizeof(float);
  bool big2 = ws_size >= need_big2;
  bool big  = ws_size >= big_bytes;
  bool mid  = ws_size >= mid_bytes;

  size_t zero_bytes = (size_t)(4 + 4 * Nn + (size_t)BN * 64) * 4;
  hipMemsetAsync(d_ws, 0, zero_bytes, stream);

  k_stats<<<dim3((Ee + 255) / 256), 256, 0, stream>>>(ea, stats);
  k_finalize_stats<<<1, 1, 0, stream>>>(stats);
  k_hist<<<dim3((Ee + 255) / 256), 256, 0, stream>>>(eidx, deg_t, deg_s);
  k_scan<<<2, 1024, 0, stream>>>(deg_t, off_t, deg_s, off_s);
  k_fill<<<dim3((Ee + 255) / 256), 256, 0, stream>>>(eidx, off_t, off_s, cur_t, cur_s, list_t, list_s);
  k_convert<<<dim3((21042 + 255) / 256), 256, 0, stream>>>(w1, b1, w2, b2, nw, nb, wih, whh, bih, bhh, fw, fb, Wf);
  k_xn0<<<dim3((BN + 255) / 256), 256, 0, stream>>>(t2m, xnA);

  for (int t = 0; t < PRED; t++) {
    float* xc  = (t & 1) ? xnB : xnA;
    float* xnx = (t & 1) ? xnA : xnB;
    if (big2) {
      k_pre_edge<<<dim3((BN + 255) / 256), 256, 0, stream>>>(feat, xc, Wf, asbuf, atbuf, t);
      k_egather<<<dim3(BN / 128), 256, 0, stream>>>(eidx, ea, off_t, list_t, off_s, list_s,
                                                    asbuf, atbuf, Wf, stats, aggbuf);
      k_gru4<<<dim3(BN / 64), 256, 0, stream>>>(aggbuf, Wf, feat, xc, xnx, hbuf, out, t);
    } else if (big) {
      k_edge<<<dim3((Ee + 255) / 256, Bb), 256, 0, stream>>>(eidx, ea, feat, xc, Wf, stats, h2buf, t);
      k_gather<<<dim3((BN + 7) / 8), 256, 0, stream>>>(off_t, list_t, off_s, list_s, h2buf, aggbuf);
      k_gru4<<<dim3(BN / 64), 256, 0, stream>>>(aggbuf, Wf, feat, xc, xnx, hbuf, out, t);
    } else if (mid) {
      k_edge<<<dim3((Ee + 255) / 256, Bb), 256, 0, stream>>>(eidx, ea, feat, xc, Wf, stats, h2buf, t);
      k_node_g<<<dim3((Nn + 63) / 64, Bb), 64, 0, stream>>>(off_t, list_t, off_s, list_s, h2buf, Wf, feat, xc, xnx, hbuf, out, t);
    } else {
      k_node_rc<<<dim3((BN + 127) / 128), 128, 0, stream>>>(eidx, ea, off_t, list_t, off_s, list_s, Wf, stats, feat, xc, xnx, hbuf, out, t);
    }
  }
}

// Round 8
// 5409.571 us; speedup vs baseline: 2.7505x; 2.7505x over previous
//
#include <hip/hip_runtime.h>
#include <hip/hip_fp16.h>
#include <hip/hip_bf16.h>

#define Bb 8
#define Nn 10000
#define Ee 320000
#define HIST 24
#define PRED 12
#define BN (Bb * Nn)

__device__ __forceinline__ float sigm(float x) { return 1.0f / (1.0f + __expf(-x)); }
__device__ __forceinline__ float tanh_fast(float x) { return 1.0f - 2.0f / (__expf(2.0f * x) + 1.0f); }

__device__ __forceinline__ void load16f(const float* p, float* o) {
  const float4* q = reinterpret_cast<const float4*>(p);
  float4 a = q[0], b = q[1], c = q[2], d = q[3];
  o[0] = a.x; o[1] = a.y; o[2]  = a.z; o[3]  = a.w;
  o[4] = b.x; o[5] = b.y; o[6]  = b.z; o[7]  = b.w;
  o[8] = c.x; o[9] = c.y; o[10] = c.z; o[11] = c.w;
  o[12] = d.x; o[13] = d.y; o[14] = d.z; o[15] = d.w;
}

// full edge MLP (fallback paths): in[35] -> sigm(35x32) -> sigm(32x30)
__device__ __forceinline__ void edge_mlp(const float* __restrict__ in,
                                         const float* __restrict__ W,
                                         float* __restrict__ h2) {
  const float* w1 = W;
  const float* b1 = W + 1120;
  const float* w2 = W + 1152;
  const float* b2 = W + 2112;
  float h1[32];
#pragma unroll
  for (int j = 0; j < 32; j++) h1[j] = b1[j];
#pragma unroll
  for (int k = 0; k < 35; k++) {
    float v = in[k];
#pragma unroll
    for (int j = 0; j < 32; j++) h1[j] = fmaf(v, w1[k * 32 + j], h1[j]);
  }
#pragma unroll
  for (int j = 0; j < 32; j++) h1[j] = sigm(h1[j]);
#pragma unroll
  for (int j = 0; j < 30; j++) h2[j] = b2[j];
#pragma unroll
  for (int k = 0; k < 32; k++) {
    float v = h1[k];
#pragma unroll
    for (int j = 0; j < 30; j++) h2[j] = fmaf(v, w2[k * 30 + j], h2[j]);
  }
#pragma unroll
  for (int j = 0; j < 30; j++) h2[j] = sigm(h2[j]);
}

// contiguous-h variant (mid/small fallback paths)
__device__ __forceinline__ void gru_out(const float* __restrict__ agg,
                                        const float* __restrict__ W,
                                        const float* __restrict__ featp,
                                        float xn_old,
                                        float* __restrict__ xn_new_slot,
                                        float* __restrict__ hp,
                                        float* __restrict__ out_slot) {
  const float* nw  = W + 2142;
  const float* nb  = W + 2532;
  const float* wih = W + 2545;
  const float* whh = W + 8305;
  const float* bih = W + 20593;
  const float* bhh = W + 20785;
  const float* fw  = W + 20977;
  const float* fcb = W + 21041;
  float xin[30];
#pragma unroll
  for (int j = 0; j < 13; j++) {
    float a = nb[j];
#pragma unroll
    for (int k = 0; k < 30; k++) a = fmaf(agg[k], nw[k * 13 + j], a);
    xin[j] = sigm(a);
  }
  xin[13] = xn_old;
  load16f(featp, xin + 14);
  float h[64];
#pragma unroll
  for (int j = 0; j < 64; j++) h[j] = hp[j];
  float xnew = fcb[0];
  for (int j = 0; j < 64; j++) {
    float ir = bih[j], iz = bih[64 + j], inn = bih[128 + j];
    const float* wr = wih + j * 30;
    const float* wz = wih + (64 + j) * 30;
    const float* wn = wih + (128 + j) * 30;
#pragma unroll
    for (int k = 0; k < 30; k++) {
      ir  = fmaf(xin[k], wr[k], ir);
      iz  = fmaf(xin[k], wz[k], iz);
      inn = fmaf(xin[k], wn[k], inn);
    }
    float hr = bhh[j], hz = bhh[64 + j], hn_ = bhh[128 + j];
    const float* vr = whh + j * 64;
    const float* vz = whh + (64 + j) * 64;
    const float* vn = whh + (128 + j) * 64;
#pragma unroll
    for (int k = 0; k < 64; k++) {
      hr  = fmaf(h[k], vr[k], hr);
      hz  = fmaf(h[k], vz[k], hz);
      hn_ = fmaf(h[k], vn[k], hn_);
    }
    float rg = sigm(ir + hr);
    float zg = sigm(iz + hz);
    float ng = tanh_fast(inn + rg * hn_);
    float hnew = (1.f - zg) * ng + zg * h[j];
    hp[j] = hnew;
    xnew = fmaf(hnew, fw[j], xnew);
  }
  *xn_new_slot = xnew;
  *out_slot = xnew;
}

// ---------- preprocessing ----------

__global__ void k_stats(const float* __restrict__ ea, float* __restrict__ stats) {
  __shared__ float s1[256], s2[256];
  int tid = threadIdx.x;
  int i = blockIdx.x * 256 + tid;
  float v = 0.f;
  if (i < Ee) v = ea[i];
  s1[tid] = v;
  s2[tid] = v * v;
  __syncthreads();
  for (int o = 128; o > 0; o >>= 1) {
    if (tid < o) { s1[tid] += s1[tid + o]; s2[tid] += s2[tid + o]; }
    __syncthreads();
  }
  if (tid == 0) { atomicAdd(&stats[0], s1[0]); atomicAdd(&stats[1], s2[0]); }
}

__global__ void k_finalize_stats(float* stats) {
  float sum = stats[0], sumsq = stats[1];
  float mean = sum / (float)Ee;
  float var = (sumsq - sum * mean) / (float)(Ee - 1);
  stats[2] = mean;
  stats[3] = rsqrtf(var);
}

__global__ void k_hist(const int* __restrict__ eidx, int* __restrict__ deg_t, int* __restrict__ deg_s) {
  int e = blockIdx.x * 256 + threadIdx.x;
  if (e >= Ee) return;
  atomicAdd(&deg_s[eidx[e]], 1);
  atomicAdd(&deg_t[eidx[Ee + e]], 1);
}

__global__ void k_scan(const int* __restrict__ deg_t, int* __restrict__ off_t,
                       const int* __restrict__ deg_s, int* __restrict__ off_s) {
  const int* deg = (blockIdx.x == 0) ? deg_t : deg_s;
  int* off = (blockIdx.x == 0) ? off_t : off_s;
  __shared__ int s[1024];
  __shared__ int carry;
  int tid = threadIdx.x;
  if (tid == 0) carry = 0;
  __syncthreads();
  for (int base = 0; base < Nn; base += 1024) {
    int v = (base + tid < Nn) ? deg[base + tid] : 0;
    s[tid] = v;
    int val = v;
    __syncthreads();
    for (int o = 1; o < 1024; o <<= 1) {
      int tv = (tid >= o) ? s[tid - o] : 0;
      __syncthreads();
      val += tv;
      s[tid] = val;
      __syncthreads();
    }
    if (base + tid < Nn) off[base + tid] = carry + (val - v);
    __syncthreads();
    if (tid == 1023) carry += val;
    __syncthreads();
  }
  if (tid == 0) off[Nn] = carry;
}

__global__ void k_fill(const int* __restrict__ eidx,
                       const int* __restrict__ off_t, const int* __restrict__ off_s,
                       int* __restrict__ cur_t, int* __restrict__ cur_s,
                       int* __restrict__ list_t, int* __restrict__ list_s) {
  int e = blockIdx.x * 256 + threadIdx.x;
  if (e >= Ee) return;
  int s = eidx[e], t = eidx[Ee + e];
  int ps = off_s[s] + atomicAdd(&cur_s[s], 1);
  list_s[ps] = e;
  int pt = off_t[t] + atomicAdd(&cur_t[t], 1);
  list_t[pt] = e;
}

__global__ void k_convert(const float* w1, const float* b1, const float* w2, const float* b2,
                          const float* nw, const float* nb, const float* wih, const float* whh,
                          const float* bih, const float* bhh, const float* fw, const float* fb,
                          float* __restrict__ dst) {
  int i = blockIdx.x * 256 + threadIdx.x;
  const int c1 = 1120, c2 = 1152, c3 = 2112, c4 = 2142, c5 = 2532, c6 = 2545,
            c7 = 8305, c8 = 20593, c9 = 20785, c10 = 20977, c11 = 21041, c12 = 21042;
  if (i >= c12) return;
  const float* p;
  int base;
  if (i < c1)       { p = w1;  base = 0;  }
  else if (i < c2)  { p = b1;  base = c1; }
  else if (i < c3)  { p = w2;  base = c2; }
  else if (i < c4)  { p = b2;  base = c3; }
  else if (i < c5)  { p = nw;  base = c4; }
  else if (i < c6)  { p = nb;  base = c5; }
  else if (i < c7)  { p = wih; base = c6; }
  else if (i < c8)  { p = whh; base = c7; }
  else if (i < c9)  { p = bih; base = c8; }
  else if (i < c10) { p = bhh; base = c9; }
  else if (i < c11) { p = fw;  base = c10; }
  else              { p = fb;  base = c11; }
  dst[i] = p[i - base];
}

__global__ void k_xn0(const float* __restrict__ t2m, float* __restrict__ xn) {
  int i = blockIdx.x * 256 + threadIdx.x;
  if (i >= BN) return;
  int b = i / Nn, n = i % Nn;
  xn[i] = t2m[((size_t)b * HIST + (HIST - 1)) * Nn + n];
}

// ---------- big2 path: hoisted layer-1 ----------

__global__ __launch_bounds__(256) void k_pre_edge(
    const float* __restrict__ feat, const float* __restrict__ xn,
    const float* __restrict__ W, float* __restrict__ as_, float* __restrict__ at_, int t) {
  int idx = blockIdx.x * 256 + threadIdx.x;
  if (idx >= BN) return;
  int b = idx / Nn, n = idx % Nn;
  const float* w1 = W;
  const float* b1 = W + 1120;
  float f[16];
  const float* fbp = feat + ((size_t)(b * (HIST + PRED) + HIST + t)) * Nn * 16 + (size_t)n * 16;
  load16f(fbp, f);
  float x = xn[idx];
  float as[32], at[32];
#pragma unroll
  for (int j = 0; j < 32; j++) {
    as[j] = fmaf(x, w1[j], b1[j]);          // row 0
    at[j] = x * w1[17 * 32 + j];            // row 17
  }
#pragma unroll
  for (int k = 0; k < 16; k++) {
    float v = f[k];
#pragma unroll
    for (int j = 0; j < 32; j++) {
      as[j] = fmaf(v, w1[(1 + k) * 32 + j], as[j]);
      at[j] = fmaf(v, w1[(18 + k) * 32 + j], at[j]);
    }
  }
  float4* ap = (float4*)(as_ + (size_t)idx * 32);
  float4* bp = (float4*)(at_ + (size_t)idx * 32);
#pragma unroll
  for (int q = 0; q < 8; q++) {
    ap[q] = make_float4(as[4 * q], as[4 * q + 1], as[4 * q + 2], as[4 * q + 3]);
    bp[q] = make_float4(at[4 * q], at[4 * q + 1], at[4 * q + 2], at[4 * q + 3]);
  }
}

// h2 layout (big2 path): h2p[e*240 + b*30 + c] halves — batch-inner, so one
// edge's 8-batch values are a contiguous 480B burst. Same total size as the
// old [b][e][30] layout (E*240 halves), so workspace is unchanged.
__global__ __launch_bounds__(256) void k_edge2(
    const int* __restrict__ eidx, const float* __restrict__ ea,
    const float* __restrict__ as_, const float* __restrict__ at_,
    const float* __restrict__ W, const float* __restrict__ stats,
    __half* __restrict__ h2p) {
  int e = blockIdx.x * 256 + threadIdx.x;
  int b = blockIdx.y;    // y-outer dispatch keeps one b's panels hot in L2
  if (e >= Ee) return;
  float mean = stats[2], istd = stats[3];
  int s = eidx[e], tg = eidx[Ee + e];
  float ean = (ea[e] - mean) * istd;
  const float* w1e = W + 34 * 32;   // w1 row 34 (edge-attr row)
  const float* w2 = W + 1152;
  const float* b2 = W + 2112;
  const float4* ap = (const float4*)(as_ + ((size_t)(b * Nn + s)) * 32);
  const float4* bp = (const float4*)(at_ + ((size_t)(b * Nn + tg)) * 32);
  float h1[32];
#pragma unroll
  for (int q = 0; q < 8; q++) {
    float4 av = ap[q], bv = bp[q];
    h1[4 * q]     = av.x + bv.x;
    h1[4 * q + 1] = av.y + bv.y;
    h1[4 * q + 2] = av.z + bv.z;
    h1[4 * q + 3] = av.w + bv.w;
  }
#pragma unroll
  for (int j = 0; j < 32; j++) h1[j] = sigm(fmaf(ean, w1e[j], h1[j]));
  float h2[30];
#pragma unroll
  for (int j = 0; j < 30; j++) h2[j] = b2[j];
#pragma unroll
  for (int k = 0; k < 32; k++) {
    float v = h1[k];
#pragma unroll
    for (int j = 0; j < 30; j++) h2[j] = fmaf(v, w2[k * 30 + j], h2[j]);
  }
  __half2* o = (__half2*)(h2p + (size_t)e * 240 + b * 30);   // even offset -> 4B aligned
#pragma unroll
  for (int i = 0; i < 15; i++) o[i] = __floats2half2_rn(sigm(h2[2 * i]), sigm(h2[2 * i + 1]));
}

// batched gather: one WAVE per node, edge lists walked ONCE for all 8 b.
// Per edge: one contiguous 480B burst (120 half2 across 64 lanes, 2 wave
// loads). Lane owns half2-pairs P0=lane and P1=lane+64 (<120); pair P maps
// to b=P/15, c=2*(P%15) (pairs never straddle b since 30 halves = 15 pairs
// per b). 8x fewer random granules + 8x fewer index reads than k_gather.
__global__ __launch_bounds__(256) void k_gather8(
    const int* __restrict__ off_t, const int* __restrict__ list_t,
    const int* __restrict__ off_s, const int* __restrict__ list_s,
    const __half* __restrict__ h2p, float* __restrict__ agg) {
  const int lane = threadIdx.x & 63;
  const int wave = threadIdx.x >> 6;
  const int n = blockIdx.x * 4 + wave;       // Nn = 2500*4 exactly
  const bool hasP1 = (lane < 56);            // P1 = lane+64 < 120

  float a0x = 0.f, a0y = 0.f, a1x = 0.f, a1y = 0.f;

  int p0 = off_t[n], p1 = off_t[n + 1];
  int p = p0;
  for (; p + 2 <= p1; p += 2) {
    int e0 = list_t[p], e1 = list_t[p + 1];
    const __half2* r0 = (const __half2*)(h2p + (size_t)e0 * 240);
    const __half2* r1 = (const __half2*)(h2p + (size_t)e1 * 240);
    __half2 u0 = r0[lane];
    __half2 v0 = r1[lane];
    __half2 u1 = hasP1 ? r0[lane + 64] : __half2{};
    __half2 v1 = hasP1 ? r1[lane + 64] : __half2{};
    a0x += __low2float(u0) + __low2float(v0);
    a0y += __high2float(u0) + __high2float(v0);
    a1x += __low2float(u1) + __low2float(v1);
    a1y += __high2float(u1) + __high2float(v1);
  }
  for (; p < p1; p++) {
    int e0 = list_t[p];
    const __half2* r0 = (const __half2*)(h2p + (size_t)e0 * 240);
    __half2 u0 = r0[lane];
    __half2 u1 = hasP1 ? r0[lane + 64] : __half2{};
    a0x += __low2float(u0); a0y += __high2float(u0);
    a1x += __low2float(u1); a1y += __high2float(u1);
  }
  p0 = off_s[n]; p1 = off_s[n + 1];
  p = p0;
  for (; p + 2 <= p1; p += 2) {
    int e0 = list_s[p], e1 = list_s[p + 1];
    const __half2* r0 = (const __half2*)(h2p + (size_t)e0 * 240);
    const __half2* r1 = (const __half2*)(h2p + (size_t)e1 * 240);
    __half2 u0 = r0[lane];
    __half2 v0 = r1[lane];
    __half2 u1 = hasP1 ? r0[lane + 64] : __half2{};
    __half2 v1 = hasP1 ? r1[lane + 64] : __half2{};
    a0x -= __low2float(u0) + __low2float(v0);
    a0y -= __high2float(u0) + __high2float(v0);
    a1x -= __low2float(u1) + __low2float(v1);
    a1y -= __high2float(u1) + __high2float(v1);
  }
  for (; p < p1; p++) {
    int e0 = list_s[p];
    const __half2* r0 = (const __half2*)(h2p + (size_t)e0 * 240);
    __half2 u0 = r0[lane];
    __half2 u1 = hasP1 ? r0[lane + 64] : __half2{};
    a0x -= __low2float(u0); a0y -= __high2float(u0);
    a1x -= __low2float(u1); a1y -= __high2float(u1);
  }

  // pair P0 = lane -> (b0, c0); P1 = lane+64 -> (b1, c1); float2 stores (8B aligned)
  {
    int b0 = lane / 15, c0 = (lane % 15) * 2;
    *(float2*)(agg + ((size_t)b0 * Nn + n) * 30 + c0) = make_float2(a0x, a0y);
    if (hasP1) {
      int P1i = lane + 64;
      int b1 = P1i / 15, c1 = (P1i % 15) * 2;
      *(float2*)(agg + ((size_t)b1 * Nn + n) * 30 + c1) = make_float2(a1x, a1y);
    }
  }
}

// old hoisted edge kernel + channel-parallel gather (fallback path, unused in big2)
__global__ __launch_bounds__(256) void k_edge(
    const int* __restrict__ eidx, const float* __restrict__ ea,
    const float* __restrict__ feat, const float* __restrict__ xn,
    const float* __restrict__ W, const float* __restrict__ stats,
    __half* __restrict__ h2out, int t) {
  int e = blockIdx.x * 256 + threadIdx.x;
  int b = blockIdx.y;
  if (e >= Ee) return;
  float mean = stats[2], istd = stats[3];
  int s = eidx[e], tg = eidx[Ee + e];
  float in[35];
  in[0]  = xn[b * Nn + s];
  in[17] = xn[b * Nn + tg];
  in[34] = (ea[e] - mean) * istd;
  const float* fb = feat + ((size_t)(b * (HIST + PRED) + HIST + t)) * Nn * 16;
  load16f(fb + (size_t)s * 16, in + 1);
  load16f(fb + (size_t)tg * 16, in + 18);
  float h2[30];
  edge_mlp(in, W, h2);
  __half2* o = (__half2*)(h2out + ((size_t)b * Ee + e) * 30);
#pragma unroll
  for (int i = 0; i < 15; i++) o[i] = __floats2half2_rn(h2[2 * i], h2[2 * i + 1]);
}

__global__ __launch_bounds__(256) void k_gather(
    const int* __restrict__ off_t, const int* __restrict__ list_t,
    const int* __restrict__ off_s, const int* __restrict__ list_s,
    const __half* __restrict__ h2, float* __restrict__ agg) {
  int tid = threadIdx.x;
  int c = tid & 31;
  int idx = blockIdx.x * 8 + (tid >> 5);
  if (idx >= BN || c >= 30) return;
  int b = idx / Nn, n = idx % Nn;
  const __half* base = h2 + (size_t)b * Ee * 30;
  float a = 0.f;
  int p0 = off_t[n], p1 = off_t[n + 1];
  int p = p0;
  for (; p + 4 <= p1; p += 4) {
    int e0 = list_t[p], e1 = list_t[p + 1], e2 = list_t[p + 2], e3 = list_t[p + 3];
    float v0 = __half2float(base[(size_t)e0 * 30 + c]);
    float v1 = __half2float(base[(size_t)e1 * 30 + c]);
    float v2 = __half2float(base[(size_t)e2 * 30 + c]);
    float v3 = __half2float(base[(size_t)e3 * 30 + c]);
    a += (v0 + v1) + (v2 + v3);
  }
  for (; p < p1; p++) a += __half2float(base[(size_t)list_t[p] * 30 + c]);
  p0 = off_s[n]; p1 = off_s[n + 1];
  p = p0;
  for (; p + 4 <= p1; p += 4) {
    int e0 = list_s[p], e1 = list_s[p + 1], e2 = list_s[p + 2], e3 = list_s[p + 3];
    float v0 = __half2float(base[(size_t)e0 * 30 + c]);
    float v1 = __half2float(base[(size_t)e1 * 30 + c]);
    float v2 = __half2float(base[(size_t)e2 * 30 + c]);
    float v3 = __half2float(base[(size_t)e3 * 30 + c]);
    a -= (v0 + v1) + (v2 + v3);
  }
  for (; p < p1; p++) a -= __half2float(base[(size_t)list_s[p] * 30 + c]);
  agg[(size_t)idx * 30 + c] = a;
}

// ---------- GRU: 4 waves per 64 nodes, j-split across waves, old-h in LDS ----------
// (round-2 winner, verbatim: duplicated per-thread prologue — measured 172us,
// FETCH 84MB; both de-dup restructures regressed to 274us / 308MB.)
#define HS_STRIDE 68

__global__ __launch_bounds__(256, 4) void k_gru4(
    const float* __restrict__ agg_all, const float* __restrict__ W,
    const float* __restrict__ feat, const float* __restrict__ xn_cur,
    float* __restrict__ xn_nxt, float* __restrict__ hbuf,
    float* __restrict__ out, int t) {
  __shared__ float hs[64 * HS_STRIDE];
  __shared__ float sx[4][64];

  const int tid = threadIdx.x;
  const int lane = tid & 63;
  const int wave = (int)__builtin_amdgcn_readfirstlane(tid >> 6);
  const int node = blockIdx.x * 64 + lane;      // BN = 1250*64 exactly
  const int b = node / Nn, n = node % Nn;

  const float* nw  = W + 2142;
  const float* nb  = W + 2532;
  const float* wih = W + 2545;
  const float* whh = W + 8305;
  const float* bih = W + 20593;
  const float* bhh = W + 20785;
  const float* fw  = W + 20977;
  const float* fcb = W + 21041;

  // ---- stage old h: wave w loads k-rows [16w,16w+16) (coalesced), LDS transpose
  float* hp = hbuf + node;
  {
    const int k0 = wave * 16;
#pragma unroll
    for (int kk = 0; kk < 16; kk++) {
      int k = k0 + kk;
      hs[lane * HS_STRIDE + k] = hp[(size_t)k * BN];
    }
  }

  // ---- node MLP -> xin[0..12] (duplicated per wave; cheap, hides LDS stage)
  float xin[30];
  {
    float agg[30];
    const float* ap = agg_all + (size_t)node * 30;
#pragma unroll
    for (int i = 0; i < 30; i++) agg[i] = ap[i];
#pragma unroll
    for (int j = 0; j < 13; j++) {
      float a = nb[j];
#pragma unroll
      for (int k = 0; k < 30; k++) a = fmaf(agg[k], nw[k * 13 + j], a);
      xin[j] = sigm(a);
    }
  }
  xin[13] = xn_cur[node];
  const float* fbp = feat + ((size_t)(b * (HIST + PRED) + HIST + t)) * Nn * 16 + (size_t)n * 16;
  load16f(fbp, xin + 14);

  __syncthreads();   // old h fully staged in LDS

  const int j0 = wave * 16;
  const float* hrow = hs + lane * HS_STRIDE;
  float xpart = 0.f;
  for (int jj = 0; jj < 16; jj++) {
    const int j = j0 + jj;      // wave-uniform -> weight rows stay scalar loads
    float ir = bih[j], iz = bih[64 + j], inn = bih[128 + j];
    const float* wr = wih + j * 30;
    const float* wz = wih + (64 + j) * 30;
    const float* wn = wih + (128 + j) * 30;
#pragma unroll
    for (int k = 0; k < 30; k++) {
      ir  = fmaf(xin[k], wr[k], ir);
      iz  = fmaf(xin[k], wz[k], iz);
      inn = fmaf(xin[k], wn[k], inn);
    }
    float hr = bhh[j], hz = bhh[64 + j], hn_ = bhh[128 + j];
    const float* vr = whh + j * 64;
    const float* vz = whh + (64 + j) * 64;
    const float* vn = whh + (128 + j) * 64;
#pragma unroll
    for (int k4 = 0; k4 < 16; k4++) {
      float4 h4 = *reinterpret_cast<const float4*>(hrow + k4 * 4);
      hr  = fmaf(h4.x, vr[4 * k4],     hr);
      hz  = fmaf(h4.x, vz[4 * k4],     hz);
      hn_ = fmaf(h4.x, vn[4 * k4],     hn_);
      hr  = fmaf(h4.y, vr[4 * k4 + 1], hr);
      hz  = fmaf(h4.y, vz[4 * k4 + 1], hz);
      hn_ = fmaf(h4.y, vn[4 * k4 + 1], hn_);
      hr  = fmaf(h4.z, vr[4 * k4 + 2], hr);
      hz  = fmaf(h4.z, vz[4 * k4 + 2], hz);
      hn_ = fmaf(h4.z, vn[4 * k4 + 2], hn_);
      hr  = fmaf(h4.w, vr[4 * k4 + 3], hr);
      hz  = fmaf(h4.w, vz[4 * k4 + 3], hz);
      hn_ = fmaf(h4.w, vn[4 * k4 + 3], hn_);
    }
    float holdj = hrow[j];      // single ds_read_b32, no register indexing
    float rg = sigm(ir + hr);
    float zg = sigm(iz + hz);
    float ng = tanh_fast(inn + rg * hn_);
    float hnew = (1.f - zg) * ng + zg * holdj;
    hp[(size_t)j * BN] = hnew;  // coalesced 256B store per (wave, j)
    xpart = fmaf(hnew, fw[j], xpart);
  }

  // reduce fc_out partials across the 4 waves
  sx[wave][lane] = xpart;
  __syncthreads();
  if (wave == 0) {
    float xnew = fcb[0] + ((sx[0][lane] + sx[1][lane]) + (sx[2][lane] + sx[3][lane]));
    xn_nxt[node] = xnew;
    out[((size_t)b * PRED + t) * Nn + n] = xnew;
  }
}

// ---------- mid path: fused gather+GRU ----------

__global__ __launch_bounds__(64) void k_node_g(
    const int* __restrict__ off_t, const int* __restrict__ list_t,
    const int* __restrict__ off_s, const int* __restrict__ list_s,
    const __half* __restrict__ h2, const float* __restrict__ W,
    const float* __restrict__ feat, const float* __restrict__ xn_cur,
    float* __restrict__ xn_nxt,
    float* __restrict__ hbuf, float* __restrict__ out, int t) {
  int n = blockIdx.x * 64 + threadIdx.x;
  int b = blockIdx.y;
  if (n >= Nn) return;
  float agg[30];
#pragma unroll
  for (int i = 0; i < 30; i++) agg[i] = 0.f;
  int p0 = off_t[n], p1 = off_t[n + 1];
  for (int p = p0; p < p1; p++) {
    int e = list_t[p];
    const __half2* r = (const __half2*)(h2 + ((size_t)b * Ee + e) * 30);
#pragma unroll
    for (int i = 0; i < 15; i++) {
      __half2 v = r[i];
      agg[2 * i]     += __low2float(v);
      agg[2 * i + 1] += __high2float(v);
    }
  }
  p0 = off_s[n]; p1 = off_s[n + 1];
  for (int p = p0; p < p1; p++) {
    int e = list_s[p];
    const __half2* r = (const __half2*)(h2 + ((size_t)b * Ee + e) * 30);
#pragma unroll
    for (int i = 0; i < 15; i++) {
      __half2 v = r[i];
      agg[2 * i]     -= __low2float(v);
      agg[2 * i + 1] -= __high2float(v);
    }
  }
  const float* fbp = feat + ((size_t)(b * (HIST + PRED) + HIST + t)) * Nn * 16 + (size_t)n * 16;
  gru_out(agg, W, fbp, xn_cur[b * Nn + n], &xn_nxt[b * Nn + n],
          hbuf + ((size_t)b * Nn + n) * 64, &out[((size_t)b * PRED + t) * Nn + n]);
}

// ---------- small path: recompute ----------

__global__ __launch_bounds__(128) void k_node_rc(
    const int* __restrict__ eidx, const float* __restrict__ ea,
    const int* __restrict__ off_t, const int* __restrict__ list_t,
    const int* __restrict__ off_s, const int* __restrict__ list_s,
    const float* __restrict__ W, const float* __restrict__ stats,
    const float* __restrict__ feat, const float* __restrict__ xn_cur,
    float* __restrict__ xn_nxt,
    float* __restrict__ hbuf, float* __restrict__ out, int t) {
  int idx = blockIdx.x * 128 + threadIdx.x;
  if (idx >= BN) return;
  int b = idx / Nn, n = idx % Nn;
  float mean = stats[2], istd = stats[3];
  const float* fslice = feat + ((size_t)(b * (HIST + PRED) + HIST + t)) * Nn * 16;
  float xo = xn_cur[b * Nn + n];
  float fo[16];
  load16f(fslice + (size_t)n * 16, fo);
  float agg[30];
#pragma unroll
  for (int i = 0; i < 30; i++) agg[i] = 0.f;
  float in[35], h2e[30];
  int p0 = off_t[n], p1 = off_t[n + 1];
  for (int p = p0; p < p1; p++) {
    int e = list_t[p];
    int s = eidx[e];
    in[0] = xn_cur[b * Nn + s];
    load16f(fslice + (size_t)s * 16, in + 1);
    in[17] = xo;
#pragma unroll
    for (int i = 0; i < 16; i++) in[18 + i] = fo[i];
    in[34] = (ea[e] - mean) * istd;
    edge_mlp(in, W, h2e);
#pragma unroll
    for (int i = 0; i < 30; i++) agg[i] += h2e[i];
  }
  p0 = off_s[n]; p1 = off_s[n + 1];
  for (int p = p0; p < p1; p++) {
    int e = list_s[p];
    int tg = eidx[Ee + e];
    in[0] = xo;
#pragma unroll
    for (int i = 0; i < 16; i++) in[1 + i] = fo[i];
    in[17] = xn_cur[b * Nn + tg];
    load16f(fslice + (size_t)tg * 16, in + 18);
    in[34] = (ea[e] - mean) * istd;
    edge_mlp(in, W, h2e);
#pragma unroll
    for (int i = 0; i < 30; i++) agg[i] -= h2e[i];
  }
  gru_out(agg, W, fslice + (size_t)n * 16, xo, &xn_nxt[b * Nn + n],
          hbuf + ((size_t)b * Nn + n) * 64, &out[((size_t)b * PRED + t) * Nn + n]);
}

// ---------- launch ----------

extern "C" void kernel_launch(void* const* d_in, const int* in_sizes, int n_in,
                              void* d_out, int out_size, void* d_ws, size_t ws_size,
                              hipStream_t stream) {
  const float* t2m  = (const float*)d_in[0];
  const float* feat = (const float*)d_in[1];
  const int*   eidx = (const int*)d_in[2];
  const float* ea   = (const float*)d_in[3];
  const float* w1   = (const float*)d_in[4];
  const float* b1   = (const float*)d_in[5];
  const float* w2   = (const float*)d_in[6];
  const float* b2   = (const float*)d_in[7];
  const float* nw   = (const float*)d_in[8];
  const float* nb   = (const float*)d_in[9];
  const float* wih  = (const float*)d_in[10];
  const float* whh  = (const float*)d_in[11];
  const float* bih  = (const float*)d_in[12];
  const float* bhh  = (const float*)d_in[13];
  const float* fw   = (const float*)d_in[14];
  const float* fb   = (const float*)d_in[15];
  float* out = (float*)d_out;

  float* ws = (float*)d_ws;
  float* stats = ws;                                   // 4
  int* deg_t = (int*)(ws + 4);                         // N
  int* deg_s = deg_t + Nn;                             // N
  int* cur_t = deg_s + Nn;                             // N
  int* cur_s = cur_t + Nn;                             // N
  float* hbuf = (float*)(cur_s + Nn);                  // B*N*64 (zeroed; transposed layout in big paths)
  int* off_t = (int*)(hbuf + (size_t)BN * 64);         // N+1
  int* off_s = off_t + (Nn + 1);                       // N+1
  int* list_t = off_s + (Nn + 1);                      // E
  int* list_s = list_t + Ee;                           // E
  float* Wf = (float*)(list_s + Ee);                   // 21056
  float* xnA = Wf + 21056;                             // B*N
  float* xnB = xnA + BN;                               // B*N
  float* base_end = xnB + BN;
  size_t base_bytes = (size_t)((char*)base_end - (char*)d_ws);
  base_bytes = (base_bytes + 15) & ~(size_t)15;
  __half* h2buf = (__half*)((char*)d_ws + base_bytes); // E*240 halves (= B*E*30, same size)
  size_t mid_bytes = base_bytes + (size_t)Bb * Ee * 30 * sizeof(__half);
  mid_bytes = (mid_bytes + 15) & ~(size_t)15;
  float* aggbuf = (float*)((char*)d_ws + mid_bytes);   // B*N*30
  size_t big_bytes = mid_bytes + (size_t)BN * 30 * sizeof(float);
  big_bytes = (big_bytes + 15) & ~(size_t)15;
  float* asbuf = (float*)((char*)d_ws + big_bytes);    // B*N*32
  float* atbuf = asbuf + (size_t)BN * 32;              // B*N*32
  size_t need_big2 = big_bytes + 2 * (size_t)BN * 32 * sizeof(float);
  bool big2 = ws_size >= need_big2;
  bool big  = ws_size >= big_bytes;
  bool mid  = ws_size >= mid_bytes;

  size_t zero_bytes = (size_t)(4 + 4 * Nn + (size_t)BN * 64) * 4;
  hipMemsetAsync(d_ws, 0, zero_bytes, stream);

  k_stats<<<dim3((Ee + 255) / 256), 256, 0, stream>>>(ea, stats);
  k_finalize_stats<<<1, 1, 0, stream>>>(stats);
  k_hist<<<dim3((Ee + 255) / 256), 256, 0, stream>>>(eidx, deg_t, deg_s);
  k_scan<<<2, 1024, 0, stream>>>(deg_t, off_t, deg_s, off_s);
  k_fill<<<dim3((Ee + 255) / 256), 256, 0, stream>>>(eidx, off_t, off_s, cur_t, cur_s, list_t, list_s);
  k_convert<<<dim3((21042 + 255) / 256), 256, 0, stream>>>(w1, b1, w2, b2, nw, nb, wih, whh, bih, bhh, fw, fb, Wf);
  k_xn0<<<dim3((BN + 255) / 256), 256, 0, stream>>>(t2m, xnA);

  for (int t = 0; t < PRED; t++) {
    float* xc  = (t & 1) ? xnB : xnA;
    float* xnx = (t & 1) ? xnA : xnB;
    if (big2) {
      k_pre_edge<<<dim3((BN + 255) / 256), 256, 0, stream>>>(feat, xc, Wf, asbuf, atbuf, t);
      k_edge2<<<dim3((Ee + 255) / 256, Bb), 256, 0, stream>>>(eidx, ea, asbuf, atbuf, Wf, stats, h2buf);
      k_gather8<<<dim3(Nn / 4), 256, 0, stream>>>(off_t, list_t, off_s, list_s, h2buf, aggbuf);
      k_gru4<<<dim3(BN / 64), 256, 0, stream>>>(aggbuf, Wf, feat, xc, xnx, hbuf, out, t);
    } else if (big) {
      k_edge<<<dim3((Ee + 255) / 256, Bb), 256, 0, stream>>>(eidx, ea, feat, xc, Wf, stats, h2buf, t);
      k_gather<<<dim3((BN + 7) / 8), 256, 0, stream>>>(off_t, list_t, off_s, list_s, h2buf, aggbuf);
      k_gru4<<<dim3(BN / 64), 256, 0, stream>>>(aggbuf, Wf, feat, xc, xnx, hbuf, out, t);
    } else if (mid) {
      k_edge<<<dim3((Ee + 255) / 256, Bb), 256, 0, stream>>>(eidx, ea, feat, xc, Wf, stats, h2buf, t);
      k_node_g<<<dim3((Nn + 63) / 64, Bb), 64, 0, stream>>>(off_t, list_t, off_s, list_s, h2buf, Wf, feat, xc, xnx, hbuf, out, t);
    } else {
      k_node_rc<<<dim3((BN + 127) / 128), 128, 0, stream>>>(eidx, ea, off_t, list_t, off_s, list_s, Wf, stats, feat, xc, xnx, hbuf, out, t);
    }
  }
}